// Round 1
// baseline (333.507 us; speedup 1.0000x reference)
//
#include <hip/hip_runtime.h>

// GraphConvolution: out[b,i,o] = relu( sum_f AX[b,i,f] * W[o,f] + bias[o] )
// AX[b,i,:] = w_i * (x[b,i-1,:] + x[b,i,:] + x[b,i+1,:]),  w_i = 1/2 ends, 1/3 interior
// x: [16384, 55, 48] fp32;  W: [48,48] fp32 (o-major);  bias: [48] fp32;  out fp32.
//
// Strategy: per-block = 4 batches. AX computed fp32 -> bf16 into LDS
// (rows r = node*4 + b_local, K padded 48->64, row stride 72 bf16 for bank spread).
// W staged bf16 in LDS once, then held entirely in registers per wave (6 frags).
// Matmul via v_mfma_f32_16x16x32_bf16: 14 M-tiles x 3 N-tiles x 2 K-steps.

#define NODES 55
#define F 48
#define BT 4              // batches per block
#define NP 56             // padded node count (14 M-tiles of 16 rows)
#define ROWS (BT * NP)    // 224
#define ST 72             // LDS row stride in bf16 elems (144 B, 16B-aligned, breaks bank conflicts)

typedef __attribute__((ext_vector_type(8))) short short8_t;
typedef __attribute__((ext_vector_type(4))) float floatx4;

__device__ __forceinline__ unsigned short f2bf(float f) {
    union { float f; unsigned int u; } v; v.f = f;
    unsigned int u = v.u;
    u += 0x7FFFu + ((u >> 16) & 1u);   // round-to-nearest-even
    return (unsigned short)(u >> 16);
}

__global__ __launch_bounds__(256, 4)
void gconv_kernel(const float* __restrict__ x, const float* __restrict__ W,
                  const float* __restrict__ bias, float* __restrict__ out) {
    __shared__ unsigned short s_ax[ROWS * ST];  // 224*72*2 = 32256 B
    __shared__ unsigned short s_w[F * ST];      // 48*72*2  =  6912 B

    const int tid = threadIdx.x;
    const int b0 = blockIdx.x * BT;

    // ---- zero only the pad regions (disjoint from staged regions -> single barrier) ----
    // k-pad (k=48..63) of real AX rows 0..219: 4 uint2 per row
    for (int i = tid; i < 220 * 4; i += 256) {
        int r = i >> 2, c = i & 3;
        *(uint2*)&s_ax[r * ST + 48 + c * 4] = make_uint2(0u, 0u);
    }
    // pad rows 220..223 (node 55) fully: 18 uint2 per row
    for (int i = tid; i < 4 * 18; i += 256) {
        int r = 220 + i / 18, c = i % 18;
        *(uint2*)&s_ax[r * ST + c * 4] = make_uint2(0u, 0u);
    }
    // W k-pad
    for (int i = tid; i < 48 * 4; i += 256) {
        int r = i >> 2, c = i & 3;
        *(uint2*)&s_w[r * ST + 48 + c * 4] = make_uint2(0u, 0u);
    }

    // ---- stage W (48x48 fp32 -> bf16) ----
    for (int i = tid; i < F * F; i += 256) {
        int o = i / 48, f = i - o * 48;
        s_w[o * ST + f] = f2bf(W[i]);
    }

    // ---- stage AX: 4 batches x 55 nodes x 12 float4-chunks ----
    const float4* xg = reinterpret_cast<const float4*>(x);
    for (int task = tid; task < BT * NODES * 12; task += 256) {   // 2640 tasks
        int b_l  = task / 660;
        int rem  = task - b_l * 660;
        int node = rem / 12;
        int fq   = rem - node * 12;
        int gidx = ((b0 + b_l) * NODES + node) * 12 + fq;
        float4 c = xg[gidx];
        float sx = c.x, sy = c.y, sz = c.z, sw = c.w;
        if (node > 0)  { float4 l = xg[gidx - 12]; sx += l.x; sy += l.y; sz += l.z; sw += l.w; }
        if (node < 54) { float4 r = xg[gidx + 12]; sx += r.x; sy += r.y; sz += r.z; sw += r.w; }
        float wgt = (node == 0 || node == 54) ? 0.5f : (1.0f / 3.0f);
        sx *= wgt; sy *= wgt; sz *= wgt; sw *= wgt;
        unsigned int lo = (unsigned int)f2bf(sx) | ((unsigned int)f2bf(sy) << 16);
        unsigned int hi = (unsigned int)f2bf(sz) | ((unsigned int)f2bf(sw) << 16);
        int r_ = node * BT + b_l;
        *(uint2*)&s_ax[r_ * ST + fq * 4] = make_uint2(lo, hi);
    }
    __syncthreads();

    // ---- MFMA phase ----
    const int lane = tid & 63;
    const int wave = tid >> 6;
    const int col  = lane & 15;    // n (or m) index within a 16x16 tile
    const int quad = lane >> 4;    // k-block selector (k = quad*8 + j)

    // all of W in registers: 3 n-tiles x 2 k-steps x 8 bf16
    short8_t wf[3][2];
#pragma unroll
    for (int nt = 0; nt < 3; ++nt)
#pragma unroll
        for (int s = 0; s < 2; ++s)
            wf[nt][s] = *(const short8_t*)&s_w[(nt * 16 + col) * ST + s * 32 + quad * 8];

    float bv[3];
#pragma unroll
    for (int nt = 0; nt < 3; ++nt) bv[nt] = bias[nt * 16 + col];

    for (int m = wave; m < 14; m += 4) {
        const int r_ = m * 16 + col;   // A-row (m index) for this lane
        short8_t a0 = *(const short8_t*)&s_ax[r_ * ST + quad * 8];
        short8_t a1 = *(const short8_t*)&s_ax[r_ * ST + 32 + quad * 8];

        floatx4 acc0 = {0.f, 0.f, 0.f, 0.f};
        floatx4 acc1 = {0.f, 0.f, 0.f, 0.f};
        floatx4 acc2 = {0.f, 0.f, 0.f, 0.f};
        acc0 = __builtin_amdgcn_mfma_f32_16x16x32_bf16(a0, wf[0][0], acc0, 0, 0, 0);
        acc1 = __builtin_amdgcn_mfma_f32_16x16x32_bf16(a0, wf[1][0], acc1, 0, 0, 0);
        acc2 = __builtin_amdgcn_mfma_f32_16x16x32_bf16(a0, wf[2][0], acc2, 0, 0, 0);
        acc0 = __builtin_amdgcn_mfma_f32_16x16x32_bf16(a1, wf[0][1], acc0, 0, 0, 0);
        acc1 = __builtin_amdgcn_mfma_f32_16x16x32_bf16(a1, wf[1][1], acc1, 0, 0, 0);
        acc2 = __builtin_amdgcn_mfma_f32_16x16x32_bf16(a1, wf[2][1], acc2, 0, 0, 0);

        // epilogue: C/D layout col=lane&15, row=quad*4+j  [m89-verified]
#pragma unroll
        for (int j = 0; j < 4; ++j) {
            int r2   = m * 16 + quad * 4 + j;
            int node = r2 >> 2;       // rows are node*4 + b_local
            int b_l  = r2 & 3;
            if (node < NODES) {
                int obase = ((b0 + b_l) * NODES + node) * F + col;
                float v0 = acc0[j] + bv[0]; v0 = v0 > 0.f ? v0 : 0.f;
                float v1 = acc1[j] + bv[1]; v1 = v1 > 0.f ? v1 : 0.f;
                float v2 = acc2[j] + bv[2]; v2 = v2 > 0.f ? v2 : 0.f;
                out[obase]      = v0;
                out[obase + 16] = v1;
                out[obase + 32] = v2;
            }
        }
    }
}

extern "C" void kernel_launch(void* const* d_in, const int* in_sizes, int n_in,
                              void* d_out, int out_size, void* d_ws, size_t ws_size,
                              hipStream_t stream) {
    const float* x    = (const float*)d_in[0];
    const float* W    = (const float*)d_in[1];
    const float* bias = (const float*)d_in[2];
    float* out = (float*)d_out;
    const int BATCH = 16384;
    dim3 grid(BATCH / BT);
    dim3 block(256);
    gconv_kernel<<<grid, block, 0, stream>>>(x, W, bias, out);
}

// Round 2
// 299.602 us; speedup vs baseline: 1.1132x; 1.1132x over previous
//
#include <hip/hip_runtime.h>

// GraphConvolution: out[b,i,o] = relu( sum_f AX[b,i,f] * W[o,f] + bias[o] )
// AX[b,i,:] = w_i * (x[b,i-1,:] + x[b,i,:] + x[b,i+1,:]),  w_i = 1/2 ends, 1/3 interior
//
// R2: latency-bound fix. Staging by node-strips: each thread owns 11 nodes of one
// (batch, feature-quad); 13 independent clamped loads issued up-front (no
// branch-serialized waitcnts). K-pad removed: second MFMA K-step gets zeros in
// quads 2-3 via register select; LDS 39.4 -> 30.5 KB.

#define NODES 55
#define F 48
#define BT 4              // batches per block
#define ROWS 224          // 56 padded nodes * BT; rows 220..223 zeroed
#define ST 56             // LDS row stride in bf16 elems (112 B): r,r+8 alias = 2-way (free)

typedef __attribute__((ext_vector_type(8))) short short8_t;
typedef __attribute__((ext_vector_type(4))) float floatx4;

__device__ __forceinline__ unsigned short f2bf(float f) {
    union { float f; unsigned int u; } v; v.f = f;
    unsigned int u = v.u;
    u += 0x7FFFu + ((u >> 16) & 1u);   // round-to-nearest-even
    return (unsigned short)(u >> 16);
}

__global__ __launch_bounds__(256, 4)
void gconv_kernel(const float* __restrict__ x, const float* __restrict__ W,
                  const float* __restrict__ bias, float* __restrict__ out) {
    __shared__ unsigned short s_ax[ROWS * ST];  // 25088 B
    __shared__ unsigned short s_w[F * ST];      //  5376 B

    const int tid = threadIdx.x;
    const int b0 = blockIdx.x * BT;

    // ---- zero tail rows 220..223 (node 55 pad), cols 0..47: threads 240..255 ----
    if (tid >= 240) {
        int i = tid - 240;
        for (int t = i; t < 48; t += 16) {           // 48 x 8B chunks
            int row = 220 + (t / 12), c = t - (t / 12) * 12;
            *(uint2*)&s_ax[row * ST + c * 4] = make_uint2(0u, 0u);
        }
    }

    // ---- stage W (48x48 fp32 -> bf16), all threads ----
    for (int i = tid; i < F * F; i += 256) {
        int o = i / 48, f = i - o * 48;
        s_w[o * ST + f] = f2bf(W[i]);
    }

    // ---- strip staging: thread = (strip s in 0..4, b_l in 0..3, fq in 0..11) ----
    if (tid < 240) {
        const int s   = tid / 48;
        const int rem = tid - s * 48;
        const int b_l = rem / 12;
        const int fq  = rem - b_l * 12;
        const float4* xg = reinterpret_cast<const float4*>(x);
        const int base = (b0 + b_l) * (NODES * 12) + fq;   // float4 index of node 0
        const int n0 = s * 11;

        // 13 independent loads, all issued before any use
        float4 v[13];
#pragma unroll
        for (int t = 0; t < 13; ++t) {
            int n = n0 - 1 + t;
            int nc = n < 0 ? 0 : (n > 54 ? 54 : n);
            float4 tmp = xg[base + nc * 12];
            bool ok = (n >= 0) & (n <= 54);
            v[t].x = ok ? tmp.x : 0.f;
            v[t].y = ok ? tmp.y : 0.f;
            v[t].z = ok ? tmp.z : 0.f;
            v[t].w = ok ? tmp.w : 0.f;
        }

#pragma unroll
        for (int t = 0; t < 11; ++t) {
            int n = n0 + t;
            float w = (n == 0 || n == 54) ? 0.5f : (1.0f / 3.0f);
            float sx = (v[t].x + v[t + 1].x + v[t + 2].x) * w;
            float sy = (v[t].y + v[t + 1].y + v[t + 2].y) * w;
            float sz = (v[t].z + v[t + 1].z + v[t + 2].z) * w;
            float sw = (v[t].w + v[t + 1].w + v[t + 2].w) * w;
            unsigned int lo = (unsigned int)f2bf(sx) | ((unsigned int)f2bf(sy) << 16);
            unsigned int hi = (unsigned int)f2bf(sz) | ((unsigned int)f2bf(sw) << 16);
            *(uint2*)&s_ax[(n * BT + b_l) * ST + fq * 4] = make_uint2(lo, hi);
        }
    }
    __syncthreads();

    // ---- MFMA phase ----
    const int lane = tid & 63;
    const int wave = tid >> 6;
    const int col  = lane & 15;    // n (or m) index within a 16x16 tile
    const int quad = lane >> 4;    // k = quad*8 + j

    const short8_t zero8 = {0, 0, 0, 0, 0, 0, 0, 0};

    // all of W in registers: 3 n-tiles x 2 k-steps; k-step 1 valid only for quads 0,1 (k=32..47)
    short8_t wf[3][2];
#pragma unroll
    for (int nt = 0; nt < 3; ++nt) {
        wf[nt][0] = *(const short8_t*)&s_w[(nt * 16 + col) * ST + quad * 8];
        short8_t t1 = *(const short8_t*)&s_w[(nt * 16 + col) * ST + 32 + (quad & 1) * 8];
        wf[nt][1] = (quad < 2) ? t1 : zero8;
    }

    float bv[3];
#pragma unroll
    for (int nt = 0; nt < 3; ++nt) bv[nt] = bias[nt * 16 + col];

    for (int m = wave; m < 14; m += 4) {
        const int r_ = m * 16 + col;   // A-row (m index) for this lane
        short8_t a0 = *(const short8_t*)&s_ax[r_ * ST + quad * 8];
        short8_t t1 = *(const short8_t*)&s_ax[r_ * ST + 32 + (quad & 1) * 8];
        short8_t a1 = (quad < 2) ? t1 : zero8;

        floatx4 acc0 = {0.f, 0.f, 0.f, 0.f};
        floatx4 acc1 = {0.f, 0.f, 0.f, 0.f};
        floatx4 acc2 = {0.f, 0.f, 0.f, 0.f};
        acc0 = __builtin_amdgcn_mfma_f32_16x16x32_bf16(a0, wf[0][0], acc0, 0, 0, 0);
        acc1 = __builtin_amdgcn_mfma_f32_16x16x32_bf16(a0, wf[1][0], acc1, 0, 0, 0);
        acc2 = __builtin_amdgcn_mfma_f32_16x16x32_bf16(a0, wf[2][0], acc2, 0, 0, 0);
        acc0 = __builtin_amdgcn_mfma_f32_16x16x32_bf16(a1, wf[0][1], acc0, 0, 0, 0);
        acc1 = __builtin_amdgcn_mfma_f32_16x16x32_bf16(a1, wf[1][1], acc1, 0, 0, 0);
        acc2 = __builtin_amdgcn_mfma_f32_16x16x32_bf16(a1, wf[2][1], acc2, 0, 0, 0);

        // epilogue: C/D layout col=lane&15, row=quad*4+j  [m89-verified]
#pragma unroll
        for (int j = 0; j < 4; ++j) {
            int r2   = m * 16 + quad * 4 + j;
            int node = r2 >> 2;       // rows are node*4 + b_local
            int b_l  = r2 & 3;
            if (node < NODES) {
                int obase = ((b0 + b_l) * NODES + node) * F + col;
                float v0 = acc0[j] + bv[0]; v0 = v0 > 0.f ? v0 : 0.f;
                float v1 = acc1[j] + bv[1]; v1 = v1 > 0.f ? v1 : 0.f;
                float v2 = acc2[j] + bv[2]; v2 = v2 > 0.f ? v2 : 0.f;
                out[obase]      = v0;
                out[obase + 16] = v1;
                out[obase + 32] = v2;
            }
        }
    }
}

extern "C" void kernel_launch(void* const* d_in, const int* in_sizes, int n_in,
                              void* d_out, int out_size, void* d_ws, size_t ws_size,
                              hipStream_t stream) {
    const float* x    = (const float*)d_in[0];
    const float* W    = (const float*)d_in[1];
    const float* bias = (const float*)d_in[2];
    float* out = (float*)d_out;
    const int BATCH = 16384;
    dim3 grid(BATCH / BT);
    dim3 block(256);
    gconv_kernel<<<grid, block, 0, stream>>>(x, W, bias, out);
}